// Round 13
// baseline (334.899 us; speedup 1.0000x reference)
//
#include <hip/hip_runtime.h>

#define NN 16384
#define FIN 128
#define FH 64
#define FO 32

typedef __attribute__((ext_vector_type(8))) short bf16x8;
typedef __attribute__((ext_vector_type(4))) float f32x4;

__device__ inline unsigned short f2bf(float f) {          // round-to-nearest-even
    unsigned int u = __float_as_uint(f);
    unsigned int r = (u + 0x7FFFu + ((u >> 16) & 1u)) >> 16;
    return (unsigned short)r;
}
__device__ inline float bf2f(unsigned short b) {
    return __uint_as_float((unsigned int)b << 16);
}

// ---------------- CSR build ----------------

__global__ void k_zero(int* __restrict__ cnt) {
    int i = blockIdx.x * 256 + threadIdx.x;
    cnt[i] = 0;
}

__global__ void k_count(const int* __restrict__ dst, int* __restrict__ cnt, int E) {
    int e = blockIdx.x * 256 + threadIdx.x;
    if (e < E) atomicAdd(&cnt[dst[e] & (NN - 1)], 1);
}

__global__ __launch_bounds__(256) void k_scan(const int* __restrict__ cnt,
                                              int* __restrict__ row) {
    __shared__ int part[256];
    __shared__ int off[257];
    int t = threadIdx.x;
    int base = t * 64;
    int s = 0;
    for (int i = 0; i < 64; ++i) s += cnt[base + i];
    part[t] = s;
    __syncthreads();
    if (t == 0) {
        int a = 0;
        for (int i = 0; i < 256; ++i) { off[i] = a; a += part[i]; }
        off[256] = a;
    }
    __syncthreads();
    int a = off[t];
    for (int i = 0; i < 64; ++i) { row[base + i] = a; a += cnt[base + i]; }
    if (t == 0) row[NN] = off[256];
}

__global__ void k_dinv(const int* __restrict__ cnt, float* __restrict__ dinv,
                       int* __restrict__ cur) {
    int i = blockIdx.x * 256 + threadIdx.x;
    dinv[i] = rsqrtf((float)cnt[i] + 1.0f);
    cur[i] = 0;
}

__global__ void k_fill(const int* __restrict__ src, const int* __restrict__ dst,
                       const int* __restrict__ row, int* __restrict__ cur,
                       const float* __restrict__ dinv,
                       int* __restrict__ csr_s, float* __restrict__ csr_w, int E) {
    int e = blockIdx.x * 256 + threadIdx.x;
    if (e >= E) return;
    int s = src[e] & (NN - 1), d = dst[e] & (NN - 1);
    int pos = atomicAdd(&cur[d], 1);
    int slot = row[d] + pos;
    csr_s[slot] = s;
    csr_w[slot] = dinv[s] * dinv[d];
}

// ---------------- dense transforms ----------------

__global__ void k_h0(const float* __restrict__ x, const float* __restrict__ W1,
                     float* __restrict__ h0) {
    int row = blockIdx.x * 4 + (threadIdx.x >> 6);
    int col = threadIdx.x & 63;
    const float* xr = x + row * FIN;
    float acc = 0.f;
#pragma unroll 8
    for (int k = 0; k < FIN; ++k)
        acc = fmaf(xr[k], W1[k * FH + col], acc);
    h0[row * FH + col] = acc;
}

__global__ void k_t(const float* __restrict__ h, const float* __restrict__ Wmu,
                    const float* __restrict__ Wls, float* __restrict__ tmu,
                    float* __restrict__ tls) {
    int row = blockIdx.x * 4 + (threadIdx.x >> 6);
    int l = threadIdx.x & 63;
    const float* hr = h + row * FH;
    const float* W = (l < 32) ? Wmu : Wls;
    int c = l & 31;
    float acc = 0.f;
#pragma unroll 8
    for (int k = 0; k < FH; ++k)
        acc = fmaf(hr[k], W[k * FO + c], acc);
    if (l < 32) tmu[row * FO + c] = acc;
    else        tls[row * FO + c] = acc;
}

// ---------------- gather propagates ----------------

__global__ void k_prop1g(const int* __restrict__ row, const int* __restrict__ csr_s,
                         const float* __restrict__ csr_w, const float* __restrict__ dinv,
                         const float* __restrict__ h0, const float* __restrict__ b1,
                         float* __restrict__ h) {
    int t = blockIdx.x * 256 + threadIdx.x;
    int i = t >> 6, l = t & 63;
    int beg = row[i], end = row[i + 1];
    float di = dinv[i];
    float acc = di * di * h0[i * FH + l];
    for (int j = beg; j < end; ++j) {
        int s = csr_s[j];
        float w = csr_w[j];
        acc = fmaf(w, h0[s * FH + l], acc);
    }
    float v = acc + b1[l];
    h[i * FH + l] = v > 0.f ? v : 0.f;
}

// layer-2 propagate + reparameterize + bf16 hi/lo split of z
__global__ void k_prop2g(const int* __restrict__ row, const int* __restrict__ csr_s,
                         const float* __restrict__ csr_w, const float* __restrict__ dinv,
                         const float* __restrict__ tmu, const float* __restrict__ tls,
                         const float* __restrict__ bmu, const float* __restrict__ bls,
                         const float* __restrict__ eps,
                         float* __restrict__ mu_out, float* __restrict__ ls_out,
                         unsigned short* __restrict__ zh, unsigned short* __restrict__ zl) {
    int t = blockIdx.x * 256 + threadIdx.x;
    int i = t >> 6, l = t & 63;
    int c = l & 31;
    int beg = row[i], end = row[i + 1];
    const float* tp = (l < 32) ? tmu : tls;
    float di = dinv[i];
    float acc = di * di * tp[i * FO + c];
    for (int j = beg; j < end; ++j) {
        int s = csr_s[j];
        float w = csr_w[j];
        acc = fmaf(w, tp[s * FO + c], acc);
    }
    float v = acc + ((l < 32) ? bmu[c] : bls[c]);
    if (l < 32) mu_out[i * FO + c] = v;
    else        ls_out[i * FO + c] = v;
    float other = __shfl_xor(v, 32);   // lane<32 gets ls
    if (l < 32) {
        float zf = fmaf(eps[i * FO + c], __expf(other), v);
        unsigned short hb = f2bf(zf);
        zh[i * FO + c] = hb;
        zl[i * FO + c] = f2bf(zf - bf2f(hb));
    }
}

// ---------------- decode: adj = sigmoid(z @ z^T) ----------------
// Tile = 16 rows x 1024 cols per block (64KB), wave w owns cols [w*256,+256).
// Writeout: each wave-store = 1KB FULLY CONTIGUOUS (one row's 256-col slice).
// Col-panel-fast block order: 16 consecutive blocks complete one 16-row band
// -> ~1MB dense rolling write window (fill-kernel-like DRAM page locality).
__global__ __launch_bounds__(256) void k_decode(const unsigned short* __restrict__ zh,
                                                const unsigned short* __restrict__ zl,
                                                float* __restrict__ out) {
    __shared__ float slab[4][16][264];   // 67.6 KB -> 2 blocks/CU, wave-private
    int bj = blockIdx.x & 15, bi = blockIdx.x >> 4;   // bj (col panel) fast
    int w = threadIdx.x >> 6;
    int l = threadIdx.x & 63;
    int lr = l & 15, lg = l >> 4;

    auto ld = [&](const unsigned short* p, int t) -> bf16x8 {
        return *(const bf16x8*)(p + ((size_t)t * 16 + lr) * FO + lg * 8);
    };

    // row fragment (rows bi*16 .. +15)
    bf16x8 rh = ld(zh, bi), rl = ld(zl, bi);

    // column fragments: 16 tiles of 16 cols for this wave
    int ctbase = bj * 64 + w * 16;
    bf16x8 ch[16], cl[16];
#pragma unroll
    for (int j = 0; j < 16; ++j) {
        ch[j] = ld(zh, ctbase + j);
        cl[j] = ld(zl, ctbase + j);
    }

#pragma unroll
    for (int j = 0; j < 16; ++j) {
        f32x4 a = {0.f, 0.f, 0.f, 0.f};
        a = __builtin_amdgcn_mfma_f32_16x16x32_bf16(ch[j], rh, a, 0, 0, 0);
        a = __builtin_amdgcn_mfma_f32_16x16x32_bf16(ch[j], rl, a, 0, 0, 0);
        a = __builtin_amdgcn_mfma_f32_16x16x32_bf16(cl[j], rh, a, 0, 0, 0);
        // lane l, reg r: S[bi*16 + lr][bj*1024 + w*256 + j*16 + lg*4 + r]
        float4 v;
        v.x = __builtin_amdgcn_rcpf(1.f + __expf(-a[0]));
        v.y = __builtin_amdgcn_rcpf(1.f + __expf(-a[1]));
        v.z = __builtin_amdgcn_rcpf(1.f + __expf(-a[2]));
        v.w = __builtin_amdgcn_rcpf(1.f + __expf(-a[3]));
        *(float4*)&slab[w][lr][j * 16 + lg * 4] = v;
    }

    // writeout: 16 insts, each = one row's 256-col slice, 1KB contiguous
#pragma unroll
    for (int r = 0; r < 16; ++r) {
        f32x4 v = *(const f32x4*)&slab[w][r][l * 4];
        f32x4* dst = (f32x4*)(out + ((size_t)(bi * 16 + r)) * NN
                              + bj * 1024 + w * 256 + l * 4);
        __builtin_nontemporal_store(v, dst);
    }
}

// ---------------- launch ----------------

extern "C" void kernel_launch(void* const* d_in, const int* in_sizes, int n_in,
                              void* d_out, int out_size, void* d_ws, size_t ws_size,
                              hipStream_t stream) {
    const float* x    = (const float*)d_in[0];
    const int*   ei   = (const int*)d_in[1];
    const float* W1   = (const float*)d_in[2];
    const float* b1   = (const float*)d_in[3];
    const float* Wmu  = (const float*)d_in[4];
    const float* bmu  = (const float*)d_in[5];
    const float* Wls  = (const float*)d_in[6];
    const float* bls  = (const float*)d_in[7];
    const float* eps  = (const float*)d_in[8];

    int E = in_sizes[1] / 2;
    const int* src = ei;
    const int* dst = ei + E;

    float* ws = (float*)d_ws;
    float* dinv  = ws;                         // NN f32
    int*   cnt   = (int*)(dinv + NN);          // NN
    int*   row   = cnt + NN;                   // NN+16
    int*   cur   = row + NN + 16;              // NN
    int*   csr_s = cur + NN;                   // E
    float* csr_w = (float*)(csr_s + E);        // E
    float* h0    = csr_w + E;                  // NN*FH
    float* h     = h0 + (size_t)NN * FH;       // NN*FH
    float* tmu   = h  + (size_t)NN * FH;       // NN*FO
    float* tls   = tmu + (size_t)NN * FO;      // NN*FO
    unsigned short* zh = (unsigned short*)(tls + (size_t)NN * FO);  // NN*FO u16
    unsigned short* zl = zh + (size_t)NN * FO;                      // NN*FO u16

    float* adj    = (float*)d_out;
    float* mu_out = adj + (size_t)NN * NN;
    float* ls_out = mu_out + (size_t)NN * FO;

    k_zero<<<NN / 256, 256, 0, stream>>>(cnt);
    k_count<<<(E + 255) / 256, 256, 0, stream>>>(dst, cnt, E);
    k_scan<<<1, 256, 0, stream>>>(cnt, row);
    k_dinv<<<NN / 256, 256, 0, stream>>>(cnt, dinv, cur);
    k_fill<<<(E + 255) / 256, 256, 0, stream>>>(src, dst, row, cur, dinv, csr_s, csr_w, E);
    k_h0<<<NN / 4, 256, 0, stream>>>(x, W1, h0);
    k_prop1g<<<NN * FH / 256, 256, 0, stream>>>(row, csr_s, csr_w, dinv, h0, b1, h);
    k_t<<<NN / 4, 256, 0, stream>>>(h, Wmu, Wls, tmu, tls);
    k_prop2g<<<NN * FH / 256, 256, 0, stream>>>(row, csr_s, csr_w, dinv, tmu, tls,
                                                bmu, bls, eps, mu_out, ls_out, zh, zl);
    k_decode<<<(NN / 16) * (NN / 1024), 256, 0, stream>>>(zh, zl, adj);
}

// Round 14
// 311.031 us; speedup vs baseline: 1.0767x; 1.0767x over previous
//
#include <hip/hip_runtime.h>

#define NN 16384
#define FIN 128
#define FH 64
#define FO 32

typedef __attribute__((ext_vector_type(8))) short bf16x8;
typedef __attribute__((ext_vector_type(4))) float f32x4;

__device__ inline unsigned short f2bf(float f) {          // round-to-nearest-even
    unsigned int u = __float_as_uint(f);
    unsigned int r = (u + 0x7FFFu + ((u >> 16) & 1u)) >> 16;
    return (unsigned short)r;
}
__device__ inline float bf2f(unsigned short b) {
    return __uint_as_float((unsigned int)b << 16);
}

// ---------------- CSR build ----------------

__global__ void k_zero(int* __restrict__ cnt) {
    int i = blockIdx.x * 256 + threadIdx.x;
    cnt[i] = 0;
}

__global__ void k_count(const int* __restrict__ dst, int* __restrict__ cnt, int E) {
    int e = blockIdx.x * 256 + threadIdx.x;
    if (e < E) atomicAdd(&cnt[dst[e] & (NN - 1)], 1);
}

// exclusive scan + dinv + cursor init, single block
__global__ __launch_bounds__(256) void k_scan(const int* __restrict__ cnt,
                                              int* __restrict__ row,
                                              float* __restrict__ dinv,
                                              int* __restrict__ cur) {
    __shared__ int part[256];
    __shared__ int off[257];
    int t = threadIdx.x;
    int base = t * 64;
    int s = 0;
    for (int i = 0; i < 64; ++i) s += cnt[base + i];
    part[t] = s;
    __syncthreads();
    if (t == 0) {
        int a = 0;
        for (int i = 0; i < 256; ++i) { off[i] = a; a += part[i]; }
        off[256] = a;
    }
    __syncthreads();
    int a = off[t];
    for (int i = 0; i < 64; ++i) {
        int c = cnt[base + i];
        row[base + i] = a; a += c;
        dinv[base + i] = rsqrtf((float)c + 1.0f);
        cur[base + i] = 0;
    }
    if (t == 0) row[NN] = off[256];
}

// fat kernel: blocks [0,nf) do CSR fill; blocks [nf, nf+NN/4) do h0 = x@W1
__global__ void k_fill_h0(const int* __restrict__ src, const int* __restrict__ dst,
                          const int* __restrict__ row, int* __restrict__ cur,
                          const float* __restrict__ dinv,
                          int* __restrict__ csr_s, float* __restrict__ csr_w, int E, int nf,
                          const float* __restrict__ x, const float* __restrict__ W1,
                          float* __restrict__ h0) {
    int b = blockIdx.x;
    if (b < nf) {
        int e = b * 256 + threadIdx.x;
        if (e >= E) return;
        int s = src[e] & (NN - 1), d = dst[e] & (NN - 1);
        int pos = atomicAdd(&cur[d], 1);
        int slot = row[d] + pos;
        csr_s[slot] = s;
        csr_w[slot] = dinv[s] * dinv[d];
    } else {
        int r = (b - nf) * 4 + (threadIdx.x >> 6);
        int col = threadIdx.x & 63;
        const float* xr = x + r * FIN;
        float acc = 0.f;
#pragma unroll 8
        for (int k = 0; k < FIN; ++k)
            acc = fmaf(xr[k], W1[k * FH + col], acc);
        h0[r * FH + col] = acc;
    }
}

// ---------------- fused layer-1 propagate + ReLU + layer-2 transform ----------
// wave per node: gather h row into one reg/lane, relu, then in-register
// matmul via __shfl broadcast (lanes 0-31 -> tmu, 32-63 -> tls).
// h is never materialized in global memory.
__global__ void k_prop1t(const int* __restrict__ row, const int* __restrict__ csr_s,
                         const float* __restrict__ csr_w, const float* __restrict__ dinv,
                         const float* __restrict__ h0, const float* __restrict__ b1,
                         const float* __restrict__ Wmu, const float* __restrict__ Wls,
                         float* __restrict__ tmu, float* __restrict__ tls) {
    int t = blockIdx.x * 256 + threadIdx.x;
    int i = t >> 6, l = t & 63;
    int beg = row[i], end = row[i + 1];
    float di = dinv[i];
    float acc = di * di * h0[i * FH + l];
    for (int j = beg; j < end; ++j) {
        int s = csr_s[j];
        float w = csr_w[j];
        acc = fmaf(w, h0[s * FH + l], acc);
    }
    float v = acc + b1[l];
    v = v > 0.f ? v : 0.f;           // h[i][l], lives in one VGPR per lane

    const float* W = (l < 32) ? Wmu : Wls;
    int c = l & 31;
    float o = 0.f;
#pragma unroll
    for (int k = 0; k < FH; ++k)
        o = fmaf(__shfl(v, k), W[k * FO + c], o);
    if (l < 32) tmu[i * FO + c] = o;
    else        tls[i * FO + c] = o;
}

// layer-2 propagate + reparameterize + bf16 hi/lo split of z
__global__ void k_prop2g(const int* __restrict__ row, const int* __restrict__ csr_s,
                         const float* __restrict__ csr_w, const float* __restrict__ dinv,
                         const float* __restrict__ tmu, const float* __restrict__ tls,
                         const float* __restrict__ bmu, const float* __restrict__ bls,
                         const float* __restrict__ eps,
                         float* __restrict__ mu_out, float* __restrict__ ls_out,
                         unsigned short* __restrict__ zh, unsigned short* __restrict__ zl) {
    int t = blockIdx.x * 256 + threadIdx.x;
    int i = t >> 6, l = t & 63;
    int c = l & 31;
    int beg = row[i], end = row[i + 1];
    const float* tp = (l < 32) ? tmu : tls;
    float di = dinv[i];
    float acc = di * di * tp[i * FO + c];
    for (int j = beg; j < end; ++j) {
        int s = csr_s[j];
        float w = csr_w[j];
        acc = fmaf(w, tp[s * FO + c], acc);
    }
    float v = acc + ((l < 32) ? bmu[c] : bls[c]);
    if (l < 32) mu_out[i * FO + c] = v;
    else        ls_out[i * FO + c] = v;
    float other = __shfl_xor(v, 32);   // lane<32 gets ls
    if (l < 32) {
        float zf = fmaf(eps[i * FO + c], __expf(other), v);
        unsigned short hb = f2bf(zf);
        zh[i * FO + c] = hb;
        zl[i * FO + c] = f2bf(zf - bf2f(hb));
    }
}

// ---------------- decode: adj = sigmoid(z @ z^T) ----------------
// 16 rows x 1024 cols per block; wave w owns cols [w*256,+256), processed in
// TWO groups of 128 cols so the slab is 34.8KB -> 4 blocks/CU (2x the
// concurrent store streams of the 67KB variant). Per-wave private slab, no
// barriers, bj-fast order, non-temporal 512B-contiguous stores.
__global__ __launch_bounds__(256, 4) void k_decode(const unsigned short* __restrict__ zh,
                                                   const unsigned short* __restrict__ zl,
                                                   float* __restrict__ out) {
    __shared__ float slab[4][16][136];   // 34.8 KB
    int bj = blockIdx.x & 15, bi = blockIdx.x >> 4;   // bj (col panel) fast
    int w = threadIdx.x >> 6;
    int l = threadIdx.x & 63;
    int lr = l & 15, lg = l >> 4;

    auto ld = [&](const unsigned short* p, int t) -> bf16x8 {
        return *(const bf16x8*)(p + ((size_t)t * 16 + lr) * FO + lg * 8);
    };

    bf16x8 rh = ld(zh, bi), rl = ld(zl, bi);   // rows bi*16..+15

    int ctbase = bj * 64 + w * 16;
#pragma unroll
    for (int g = 0; g < 2; ++g) {
        // stage 8 col-tiles (128 cols) into the slab
#pragma unroll
        for (int j = 0; j < 8; ++j) {
            int ct = ctbase + g * 8 + j;
            bf16x8 ch = ld(zh, ct);
            bf16x8 cl = ld(zl, ct);
            f32x4 a = {0.f, 0.f, 0.f, 0.f};
            a = __builtin_amdgcn_mfma_f32_16x16x32_bf16(ch, rh, a, 0, 0, 0);
            a = __builtin_amdgcn_mfma_f32_16x16x32_bf16(ch, rl, a, 0, 0, 0);
            a = __builtin_amdgcn_mfma_f32_16x16x32_bf16(cl, rh, a, 0, 0, 0);
            float4 v;
            v.x = __builtin_amdgcn_rcpf(1.f + __expf(-a[0]));
            v.y = __builtin_amdgcn_rcpf(1.f + __expf(-a[1]));
            v.z = __builtin_amdgcn_rcpf(1.f + __expf(-a[2]));
            v.w = __builtin_amdgcn_rcpf(1.f + __expf(-a[3]));
            *(float4*)&slab[w][lr][j * 16 + lg * 4] = v;
        }
        // write out: 16 insts, each = 2 rows x 512B contiguous
        size_t cbase = (size_t)bj * 1024 + w * 256 + g * 128;
#pragma unroll
        for (int inst = 0; inst < 8; ++inst) {
            int r = inst * 2 + (l >> 5);
            int f4 = l & 31;
            f32x4 v = *(const f32x4*)&slab[w][r][f4 * 4];
            f32x4* dst = (f32x4*)(out + ((size_t)(bi * 16 + r)) * NN + cbase + f4 * 4);
            __builtin_nontemporal_store(v, dst);
        }
#pragma unroll
        for (int inst = 8; inst < 16; ++inst) {
            int r = (inst - 8) * 2 + (l >> 5) + 0;   // rows 0..15 second half below
            int r2 = inst * 2 - 16 + (l >> 5) + 0;
            (void)r; (void)r2;
        }
        // (rows 0..15 all covered above: inst 0..7 -> rows 0..15 via 2/inst)
    }
}

// ---------------- launch ----------------

extern "C" void kernel_launch(void* const* d_in, const int* in_sizes, int n_in,
                              void* d_out, int out_size, void* d_ws, size_t ws_size,
                              hipStream_t stream) {
    const float* x    = (const float*)d_in[0];
    const int*   ei   = (const int*)d_in[1];
    const float* W1   = (const float*)d_in[2];
    const float* b1   = (const float*)d_in[3];
    const float* Wmu  = (const float*)d_in[4];
    const float* bmu  = (const float*)d_in[5];
    const float* Wls  = (const float*)d_in[6];
    const float* bls  = (const float*)d_in[7];
    const float* eps  = (const float*)d_in[8];

    int E = in_sizes[1] / 2;
    int nf = (E + 255) / 256;
    const int* src = ei;
    const int* dst = ei + E;

    float* ws = (float*)d_ws;
    float* dinv  = ws;                         // NN f32
    int*   cnt   = (int*)(dinv + NN);          // NN
    int*   row   = cnt + NN;                   // NN+16
    int*   cur   = row + NN + 16;              // NN
    int*   csr_s = cur + NN;                   // E
    float* csr_w = (float*)(csr_s + E);        // E
    float* h0    = csr_w + E;                  // NN*FH
    float* tmu   = h0 + (size_t)NN * FH;       // NN*FO
    float* tls   = tmu + (size_t)NN * FO;      // NN*FO
    unsigned short* zh = (unsigned short*)(tls + (size_t)NN * FO);  // NN*FO u16
    unsigned short* zl = zh + (size_t)NN * FO;                      // NN*FO u16

    float* adj    = (float*)d_out;
    float* mu_out = adj + (size_t)NN * NN;
    float* ls_out = mu_out + (size_t)NN * FO;

    k_zero<<<NN / 256, 256, 0, stream>>>(cnt);
    k_count<<<nf, 256, 0, stream>>>(dst, cnt, E);
    k_scan<<<1, 256, 0, stream>>>(cnt, row, dinv, cur);
    k_fill_h0<<<nf + NN / 4, 256, 0, stream>>>(src, dst, row, cur, dinv,
                                               csr_s, csr_w, E, nf, x, W1, h0);
    k_prop1t<<<NN * FH / 256, 256, 0, stream>>>(row, csr_s, csr_w, dinv, h0, b1,
                                                Wmu, Wls, tmu, tls);
    k_prop2g<<<NN * FH / 256, 256, 0, stream>>>(row, csr_s, csr_w, dinv, tmu, tls,
                                                bmu, bls, eps, mu_out, ls_out, zh, zl);
    k_decode<<<(NN / 16) * (NN / 1024), 256, 0, stream>>>(zh, zl, adj);
}